// Round 5
// baseline (1711.681 us; speedup 1.0000x reference)
//
#include <hip/hip_runtime.h>
#include <hip/hip_bf16.h>
#include <math.h>

// Problem constants (B=2048, D=512, C=100000)
constexpr int Bq = 2048;
constexpr int Dq = 512;
constexpr int Cq = 100000;
constexpr int NPAD = 100096;     // 391 * 256 (N padded to tile multiple)

constexpr float SCALE = 64.0f;
constexpr float COS_M = 0.8775825618903728f;   // cos(0.5)
constexpr float SIN_M = 0.479425538604203f;    // sin(0.5)
constexpr float THR   = -0.8775825618903728f;  // cos(pi - 0.5)
constexpr float MM    = 0.2397127693021015f;   // sin(pi - 0.5) * 0.5

typedef __attribute__((ext_vector_type(8))) __bf16 bf16x8;
typedef __attribute__((ext_vector_type(4))) float f32x4;

typedef const __attribute__((address_space(1))) unsigned int guint;
typedef __attribute__((address_space(3))) unsigned int suint;

__device__ __forceinline__ void gload_lds16(const unsigned short* g, unsigned short* lds)
{
    __builtin_amdgcn_global_load_lds((guint*)g, (suint*)lds, 16, 0, 0);
}

__device__ __forceinline__ unsigned int pack_bf16x2(float lo, float hi)
{
    __hip_bfloat16 h0 = __float2bfloat16(lo);
    __hip_bfloat16 h1 = __float2bfloat16(hi);
    return ((unsigned int)(*(unsigned short*)&h1) << 16) |
           (unsigned int)(*(unsigned short*)&h0);
}

// ---------------------------------------------------------------------------
// Row L2-normalize fp32 [*][512] -> bf16, wave-per-row, float4 loads,
// pure shuffle reduce. 4 rows per 256-thread block. Pad rows write zeros.
// ---------------------------------------------------------------------------
__global__ __launch_bounds__(256) void normalize_rows_kernel(
    const float* __restrict__ in, unsigned short* __restrict__ out, int nrows)
{
    const int w = threadIdx.x >> 6, lane = threadIdx.x & 63;
    const int row = blockIdx.x * 4 + w;
    float4 a = {0.f, 0.f, 0.f, 0.f}, b = a;
    if (row < nrows) {
        const float4* src = reinterpret_cast<const float4*>(in + (size_t)row * Dq);
        a = src[lane];
        b = src[lane + 64];
    }
    float ss = a.x * a.x + a.y * a.y + a.z * a.z + a.w * a.w
             + b.x * b.x + b.y * b.y + b.z * b.z + b.w * b.w;
    #pragma unroll
    for (int off = 32; off > 0; off >>= 1) ss += __shfl_down(ss, off);
    ss = __shfl(ss, 0);
    const float invn = 1.0f / fmaxf(sqrtf(ss), 1e-12f);

    uint2* out64 = reinterpret_cast<uint2*>(out + (size_t)row * Dq);
    uint2 pa, pb;
    pa.x = pack_bf16x2(a.x * invn, a.y * invn);
    pa.y = pack_bf16x2(a.z * invn, a.w * invn);
    pb.x = pack_bf16x2(b.x * invn, b.y * invn);
    pb.y = pack_bf16x2(b.z * invn, b.w * invn);
    out64[lane] = pa;
    out64[lane + 64] = pb;
}

// ---------------------------------------------------------------------------
// 256x256 GEMM, BK=64, 8 waves (2M x 4N), SINGLE-buffered 64KB LDS ->
// 2 blocks/CU. Per K-step: [bar] stage 8 units [vmcnt(0)] [bar] compute.
// The per-kt stage wait and the end-of-block 256KB store drain are hidden by
// the co-resident block's MFMA/LDS work (this was the round-4 bottleneck:
// 1 block/CU serialized the write drain against the next block's prologue).
// T2 involution swizzle on LDS chunks, T1 XCD block swizzle, T5 setprio,
// swapped-operand MFMA so the epilogue stores f32x4 per acc group.
// ---------------------------------------------------------------------------
__global__ __launch_bounds__(512, 4) void arc_gemm_kernel(
    const unsigned short* __restrict__ A,
    const unsigned short* __restrict__ Bn,
    const int* __restrict__ labels,
    float* __restrict__ out)
{
    extern __shared__ unsigned short lds[];   // 65536 B: A 32KB | B 32KB

    // T1: XCD-aware bijective swizzle (3128 = 8 * 391 exact)
    const int cpx = (int)gridDim.x >> 3;
    const int bid = ((int)blockIdx.x & 7) * cpx + ((int)blockIdx.x >> 3);
    const int tm = bid & 7;          // 8 m-tiles share one B-strip per XCD
    const int tn = bid >> 3;
    const int m0 = tm * 256, n0 = tn * 256;

    const int t = threadIdx.x;
    const int w = t >> 6, lane = t & 63;
    const int wr = (w >> 2) * 128;   // wave M (emb) origin
    const int wc = (w & 3) * 64;     // wave N (class) origin
    const int fr = lane & 15, kg = lane >> 4;
    const int s7 = fr & 7;
    const int c0 = (kg ^ s7) * 8;          // swizzled chunk, ks=0 (elems)
    const int c1 = ((4 + kg) ^ s7) * 8;    // ks=1

    // staging: thread t covers row trow of each 64-row unit, swizzled src col
    const int trow = t >> 3;
    const int tch = ((t & 7) ^ (trow & 7)) * 8;
    const unsigned short* gA = A  + (size_t)(m0 + trow) * Dq + tch;
    const unsigned short* gB = Bn + (size_t)(n0 + trow) * Dq + tch;
    const int dstA = trow * 64 + (t & 7) * 8;   // linear LDS dest (= lane*16 B)

#define STAGE_A(u, kts) gload_lds16(gA + (size_t)(u) * 64 * Dq + (size_t)(kts) * 64, \
                                    &lds[(u) * 4096 + dstA])
#define STAGE_B(u, kts) gload_lds16(gB + (size_t)(u) * 64 * Dq + (size_t)(kts) * 64, \
                                    &lds[16384 + (u) * 4096 + dstA])
#define BARRIER() do { __builtin_amdgcn_sched_barrier(0); __builtin_amdgcn_s_barrier(); } while (0)

    f32x4 acc[8][4];
    #pragma unroll
    for (int i = 0; i < 8; ++i)
        #pragma unroll
        for (int j = 0; j < 4; ++j) acc[i][j] = {0.f, 0.f, 0.f, 0.f};

    const int arow = (wr + fr) * 64;
    const int brow = 16384 + (wc + fr) * 64;

#define LDA(q) do { \
    _Pragma("unroll") for (int m2 = 0; m2 < 2; ++m2) { \
        afr[m2][0] = *reinterpret_cast<const bf16x8*>(&lds[arow + ((q) * 32 + m2 * 16) * 64 + c0]); \
        afr[m2][1] = *reinterpret_cast<const bf16x8*>(&lds[arow + ((q) * 32 + m2 * 16) * 64 + c1]); } \
} while (0)
#define LDB() do { \
    _Pragma("unroll") for (int ni = 0; ni < 4; ++ni) { \
        bfr[ni][0] = *reinterpret_cast<const bf16x8*>(&lds[brow + ni * 1024 + c0]); \
        bfr[ni][1] = *reinterpret_cast<const bf16x8*>(&lds[brow + ni * 1024 + c1]); } \
} while (0)
// Operands swapped: A-operand = class frag (bfr), B-operand = emb frag (afr).
#define MFMA_QUAD(q) do { \
    __builtin_amdgcn_s_setprio(1); \
    _Pragma("unroll") for (int ks = 0; ks < 2; ++ks) \
    _Pragma("unroll") for (int m2 = 0; m2 < 2; ++m2) \
    _Pragma("unroll") for (int ni = 0; ni < 4; ++ni) \
        acc[2 * (q) + m2][ni] = __builtin_amdgcn_mfma_f32_16x16x32_bf16( \
            bfr[ni][ks], afr[m2][ks], acc[2 * (q) + m2][ni], 0, 0, 0); \
    __builtin_amdgcn_s_setprio(0); \
} while (0)

    #pragma unroll
    for (int kt = 0; kt < 8; ++kt) {
        // all waves finished reading slab kt-1 (every ds_read fed an MFMA
        // whose lgkmcnt wait preceded the wave's arrival here)
        BARRIER();
        STAGE_A(0, kt); STAGE_A(1, kt); STAGE_A(2, kt); STAGE_A(3, kt);
        STAGE_B(0, kt); STAGE_B(1, kt); STAGE_B(2, kt); STAGE_B(3, kt);
        asm volatile("s_waitcnt vmcnt(0)" ::: "memory");
        BARRIER();
        bf16x8 bfr[4][2];
        bf16x8 afr[2][2];
        LDB();
        LDA(0); MFMA_QUAD(0);
        LDA(1); MFMA_QUAD(1);
        LDA(2); MFMA_QUAD(2);
        LDA(3); MFMA_QUAD(3);
    }

    // Epilogue (swapped-operand D mapping):
    //   emb row   = m0 + wr + mi*16 + fr
    //   class col = n0 + wc + ni*16 + kg*4 + reg  -> f32x4 = 4 consecutive cols
    const int ccol0 = wc + kg * 4;
    #pragma unroll
    for (int mi = 0; mi < 8; ++mi) {
        const int grow = m0 + wr + mi * 16 + fr;
        const int lab = labels[grow];
        float* orow = out + (size_t)grow * Cq + n0;
        #pragma unroll
        for (int ni = 0; ni < 4; ++ni) {
            const int col0 = ccol0 + ni * 16;
            const int gcol0 = n0 + col0;
            if (gcol0 >= Cq) continue;   // whole vector in padding (both %4==0)
            f32x4 v = acc[mi][ni];
            #pragma unroll
            for (int r = 0; r < 4; ++r) {
                if (gcol0 + r == lab) {
                    float c = v[r];
                    float sine = sqrtf(fmaxf(1.0f - c * c, 0.0f));
                    float phi = c * COS_M - sine * SIN_M;
                    v[r] = (c > THR) ? phi : (c - MM);
                }
            }
            v *= SCALE;
            *reinterpret_cast<f32x4*>(orow + col0) = v;   // 16B-aligned dwordx4
        }
    }
#undef STAGE_A
#undef STAGE_B
#undef BARRIER
#undef LDA
#undef LDB
#undef MFMA_QUAD
}

extern "C" void kernel_launch(void* const* d_in, const int* in_sizes, int n_in,
                              void* d_out, int out_size, void* d_ws, size_t ws_size,
                              hipStream_t stream)
{
    const float* emb    = (const float*)d_in[0];
    const int*   labels = (const int*)d_in[1];
    const float* weight = (const float*)d_in[2];
    float* out = (float*)d_out;

    unsigned short* Abf = (unsigned short*)d_ws;             // 2 MB
    unsigned short* Bbf = Abf + (size_t)Bq * Dq;             // 102.5 MB

    normalize_rows_kernel<<<Bq / 4, 256, 0, stream>>>(emb, Abf, Bq);
    normalize_rows_kernel<<<NPAD / 4, 256, 0, stream>>>(weight, Bbf, Cq);
    arc_gemm_kernel<<<8 * (NPAD / 256), 512, 65536, stream>>>(Abf, Bbf, labels, out);
}

// Round 6
// 547.920 us; speedup vs baseline: 3.1240x; 3.1240x over previous
//
#include <hip/hip_runtime.h>
#include <hip/hip_bf16.h>
#include <math.h>

// Problem constants (B=2048, D=512, C=100000)
constexpr int Bq = 2048;
constexpr int Dq = 512;
constexpr int Cq = 100000;
constexpr int NPAD = 100096;     // 782 * 128

constexpr float SCALE = 64.0f;
constexpr float COS_M = 0.8775825618903728f;   // cos(0.5)
constexpr float SIN_M = 0.479425538604203f;    // sin(0.5)
constexpr float THR   = -0.8775825618903728f;  // cos(pi - 0.5)
constexpr float MM    = 0.2397127693021015f;   // sin(pi - 0.5) * 0.5

typedef __attribute__((ext_vector_type(8))) __bf16 bf16x8;
typedef __attribute__((ext_vector_type(4))) float f32x4;

typedef const __attribute__((address_space(1))) unsigned int guint;
typedef __attribute__((address_space(3))) unsigned int suint;

__device__ __forceinline__ void gload_lds16(const unsigned short* g, unsigned short* lds)
{
    __builtin_amdgcn_global_load_lds((guint*)g, (suint*)lds, 16, 0, 0);
}

__device__ __forceinline__ unsigned int pack_bf16x2(float lo, float hi)
{
    __hip_bfloat16 h0 = __float2bfloat16(lo);
    __hip_bfloat16 h1 = __float2bfloat16(hi);
    return ((unsigned int)(*(unsigned short*)&h1) << 16) |
           (unsigned int)(*(unsigned short*)&h0);
}

// ---------------------------------------------------------------------------
// Row L2-normalize fp32 [*][512] -> bf16, wave-per-row, float4 loads,
// pure shuffle reduce. 4 rows per 256-thread block. Pad rows write zeros.
// ---------------------------------------------------------------------------
__global__ __launch_bounds__(256) void normalize_rows_kernel(
    const float* __restrict__ in, unsigned short* __restrict__ out, int nrows)
{
    const int w = threadIdx.x >> 6, lane = threadIdx.x & 63;
    const int row = blockIdx.x * 4 + w;
    float4 a = {0.f, 0.f, 0.f, 0.f}, b = a;
    if (row < nrows) {
        const float4* src = reinterpret_cast<const float4*>(in + (size_t)row * Dq);
        a = src[lane];
        b = src[lane + 64];
    }
    float ss = a.x * a.x + a.y * a.y + a.z * a.z + a.w * a.w
             + b.x * b.x + b.y * b.y + b.z * b.z + b.w * b.w;
    #pragma unroll
    for (int off = 32; off > 0; off >>= 1) ss += __shfl_down(ss, off);
    ss = __shfl(ss, 0);
    const float invn = 1.0f / fmaxf(sqrtf(ss), 1e-12f);

    uint2* out64 = reinterpret_cast<uint2*>(out + (size_t)row * Dq);
    uint2 pa, pb;
    pa.x = pack_bf16x2(a.x * invn, a.y * invn);
    pa.y = pack_bf16x2(a.z * invn, a.w * invn);
    pb.x = pack_bf16x2(b.x * invn, b.y * invn);
    pb.y = pack_bf16x2(b.z * invn, b.w * invn);
    out64[lane] = pa;
    out64[lane + 64] = pb;
}

// ---------------------------------------------------------------------------
// 128x128 GEMM tile, BK=32, kt=16, 256 threads (4 waves, 2M x 2N, 64x64 each),
// double-buffered LDS 32KB -> 4 blocks/CU (launch_bounds(256,4): VGPR cap 128,
// 16 waves/CU). T3/T4 counted-vmcnt 2-deep pipeline:
//   prologue: stage kt0+kt1 (8 units), vmcnt(4), barrier
//   per kt: ds_read 8 frags; lgkm(0); barrier; stage kt+2 (4 units, same buf);
//           16 MFMA (setprio); vmcnt(4) [kt+1 landed]; barrier
// Per-CU HBM write drain (64KB/block) now overlaps co-resident blocks' MFMA.
// LDS rows are 64B (32 bf16); swizzle: chunk c' = c ^ ((row>>1)&3), applied
// as pre-swizzled GLOBAL source chunk (linear gload_lds dest) + XOR'd ds_read.
// Swapped-operand MFMA: D lane fragment = 4 consecutive class cols of one
// emb row -> f32x4 epilogue stores.
// ---------------------------------------------------------------------------
__global__ __launch_bounds__(256, 4) void arc_gemm_kernel(
    const unsigned short* __restrict__ A,
    const unsigned short* __restrict__ Bn,
    const int* __restrict__ labels,
    float* __restrict__ out)
{
    __shared__ unsigned short lds[16384];   // 32 KB: 2 x (A 8KB | B 8KB)

    // T1: XCD-aware bijective swizzle (12512 = 8 * 1564 exact)
    const int cpx = (int)gridDim.x >> 3;
    const int bid = ((int)blockIdx.x & 7) * cpx + ((int)blockIdx.x >> 3);
    const int tm = bid & 15;         // 16 m-tiles share one B-strip per XCD
    const int tn = bid >> 4;
    const int m0 = tm * 128, n0 = tn * 128;

    const int t = threadIdx.x;
    const int w = t >> 6, lane = t & 63;
    const int wr = (w >> 1) * 64;    // wave M (emb) origin
    const int wc = (w & 1) * 64;     // wave N (class) origin
    const int fr = lane & 15, kg = lane >> 4;
    const int cfrag = (kg ^ ((fr >> 1) & 3)) * 8;   // swizzled chunk (elems)

    // staging: thread t covers row t>>2 of each 64-row unit, 16B chunk t&3,
    // global source chunk pre-swizzled by ((t>>2)>>1)&3 = (t>>3)&3
    const int trow = t >> 2;
    const int sch = ((t & 3) ^ ((t >> 3) & 3)) * 8;
    const unsigned short* gA = A  + (size_t)(m0 + trow) * Dq + sch;
    const unsigned short* gB = Bn + (size_t)(n0 + trow) * Dq + sch;
    const int dst = t * 8;   // lane-linear LDS dest (= lane*16B within wave)

#define STAGE_A(buf, u, kts) gload_lds16(gA + (size_t)(u) * 64 * Dq + (kts) * 32, \
                                         &lds[(buf) * 8192 + (u) * 2048 + dst])
#define STAGE_B(buf, u, kts) gload_lds16(gB + (size_t)(u) * 64 * Dq + (kts) * 32, \
                                         &lds[(buf) * 8192 + 4096 + (u) * 2048 + dst])

    f32x4 acc[4][4];
    #pragma unroll
    for (int i = 0; i < 4; ++i)
        #pragma unroll
        for (int j = 0; j < 4; ++j) acc[i][j] = {0.f, 0.f, 0.f, 0.f};

    // Prologue: kt0 + kt1 fully staged (8 units)
    STAGE_A(0, 0, 0); STAGE_A(0, 1, 0); STAGE_B(0, 0, 0); STAGE_B(0, 1, 0);
    STAGE_A(1, 0, 1); STAGE_A(1, 1, 1); STAGE_B(1, 0, 1); STAGE_B(1, 1, 1);
    asm volatile("s_waitcnt vmcnt(4)" ::: "memory");   // kt0 landed
    __builtin_amdgcn_sched_barrier(0);
    __builtin_amdgcn_s_barrier();

    const int arow = (wr + fr) * 32 + cfrag;          // A frag base (mi=0)
    const int brow = 4096 + (wc + fr) * 32 + cfrag;   // B frag base (ni=0)

    #pragma unroll
    for (int kt = 0; kt < 16; ++kt) {
        const int cb = kt & 1;
        const int cbo = cb * 8192;
        bf16x8 afr[4], bfr[4];
        #pragma unroll
        for (int mi = 0; mi < 4; ++mi)
            afr[mi] = *reinterpret_cast<const bf16x8*>(&lds[cbo + arow + mi * 512]);
        #pragma unroll
        for (int ni = 0; ni < 4; ++ni)
            bfr[ni] = *reinterpret_cast<const bf16x8*>(&lds[cbo + brow + ni * 512]);
        asm volatile("s_waitcnt lgkmcnt(0)" ::: "memory");  // frags in regs
        __builtin_amdgcn_sched_barrier(0);
        __builtin_amdgcn_s_barrier();                       // all waves read slab kt
        if (kt < 14) {   // restage same buffer with kt+2
            STAGE_A(cb, 0, kt + 2); STAGE_A(cb, 1, kt + 2);
            STAGE_B(cb, 0, kt + 2); STAGE_B(cb, 1, kt + 2);
        }
        __builtin_amdgcn_s_setprio(1);
        #pragma unroll
        for (int mi = 0; mi < 4; ++mi)
            #pragma unroll
            for (int ni = 0; ni < 4; ++ni)
                acc[mi][ni] = __builtin_amdgcn_mfma_f32_16x16x32_bf16(
                    bfr[ni], afr[mi], acc[mi][ni], 0, 0, 0);   // swapped operands
        __builtin_amdgcn_s_setprio(0);
        if (kt < 14)       asm volatile("s_waitcnt vmcnt(4)" ::: "memory"); // kt+1 landed
        else if (kt == 14) asm volatile("s_waitcnt vmcnt(0)" ::: "memory"); // kt15 landed
        __builtin_amdgcn_sched_barrier(0);
        __builtin_amdgcn_s_barrier();
    }

    // Epilogue (swapped-operand D mapping):
    //   emb row   = m0 + wr + mi*16 + fr
    //   class col = n0 + wc + ni*16 + kg*4 + reg  -> f32x4 = 4 consecutive cols
    const int ccol0 = wc + kg * 4;
    #pragma unroll
    for (int mi = 0; mi < 4; ++mi) {
        const int grow = m0 + wr + mi * 16 + fr;
        const int lab = labels[grow];
        float* orow = out + (size_t)grow * Cq + n0;
        #pragma unroll
        for (int ni = 0; ni < 4; ++ni) {
            const int col0 = ccol0 + ni * 16;
            const int gcol0 = n0 + col0;
            if (gcol0 >= Cq) continue;   // whole vector in padding (both %4==0)
            f32x4 v = acc[mi][ni];
            #pragma unroll
            for (int r = 0; r < 4; ++r) {
                if (gcol0 + r == lab) {
                    float c = v[r];
                    float sine = sqrtf(fmaxf(1.0f - c * c, 0.0f));
                    float phi = c * COS_M - sine * SIN_M;
                    v[r] = (c > THR) ? phi : (c - MM);
                }
            }
            v *= SCALE;
            *reinterpret_cast<f32x4*>(orow + col0) = v;   // 16B-aligned dwordx4
        }
    }
#undef STAGE_A
#undef STAGE_B
}

extern "C" void kernel_launch(void* const* d_in, const int* in_sizes, int n_in,
                              void* d_out, int out_size, void* d_ws, size_t ws_size,
                              hipStream_t stream)
{
    const float* emb    = (const float*)d_in[0];
    const int*   labels = (const int*)d_in[1];
    const float* weight = (const float*)d_in[2];
    float* out = (float*)d_out;

    unsigned short* Abf = (unsigned short*)d_ws;             // 2 MB
    unsigned short* Bbf = Abf + (size_t)Bq * Dq;             // 102.5 MB

    normalize_rows_kernel<<<Bq / 4, 256, 0, stream>>>(emb, Abf, Bq);
    normalize_rows_kernel<<<NPAD / 4, 256, 0, stream>>>(weight, Bbf, Cq);
    arc_gemm_kernel<<<16 * (NPAD / 128), 256, 0, stream>>>(Abf, Bbf, labels, out);
}

// Round 7
// 382.925 us; speedup vs baseline: 4.4700x; 1.4309x over previous
//
#include <hip/hip_runtime.h>
#include <hip/hip_bf16.h>
#include <math.h>

// Problem constants (B=2048, D=512, C=100000)
constexpr int Bq = 2048;
constexpr int Dq = 512;
constexpr int Cq = 100000;
constexpr int NPAD = 100096;     // 391 * 256 (N padded to tile multiple)

constexpr float SCALE = 64.0f;
constexpr float COS_M = 0.8775825618903728f;   // cos(0.5)
constexpr float SIN_M = 0.479425538604203f;    // sin(0.5)
constexpr float THR   = -0.8775825618903728f;  // cos(pi - 0.5)
constexpr float MM    = 0.2397127693021015f;   // sin(pi - 0.5) * 0.5

typedef __attribute__((ext_vector_type(8))) __bf16 bf16x8;
typedef __attribute__((ext_vector_type(4))) float f32x4;

typedef const __attribute__((address_space(1))) unsigned int guint;
typedef __attribute__((address_space(3))) unsigned int suint;

__device__ __forceinline__ void gload_lds16(const unsigned short* g, unsigned short* lds)
{
    __builtin_amdgcn_global_load_lds((guint*)g, (suint*)lds, 16, 0, 0);
}

__device__ __forceinline__ unsigned int pack_bf16x2(float lo, float hi)
{
    __hip_bfloat16 h0 = __float2bfloat16(lo);
    __hip_bfloat16 h1 = __float2bfloat16(hi);
    return ((unsigned int)(*(unsigned short*)&h1) << 16) |
           (unsigned int)(*(unsigned short*)&h0);
}

// ---------------------------------------------------------------------------
// Row L2-normalize fp32 [*][512] -> bf16, wave-per-row, float4 loads,
// pure shuffle reduce. 4 rows per 256-thread block. Pad rows write zeros.
// ---------------------------------------------------------------------------
__global__ __launch_bounds__(256) void normalize_rows_kernel(
    const float* __restrict__ in, unsigned short* __restrict__ out, int nrows)
{
    const int w = threadIdx.x >> 6, lane = threadIdx.x & 63;
    const int row = blockIdx.x * 4 + w;
    float4 a = {0.f, 0.f, 0.f, 0.f}, b = a;
    if (row < nrows) {
        const float4* src = reinterpret_cast<const float4*>(in + (size_t)row * Dq);
        a = src[lane];
        b = src[lane + 64];
    }
    float ss = a.x * a.x + a.y * a.y + a.z * a.z + a.w * a.w
             + b.x * b.x + b.y * b.y + b.z * b.z + b.w * b.w;
    #pragma unroll
    for (int off = 32; off > 0; off >>= 1) ss += __shfl_down(ss, off);
    ss = __shfl(ss, 0);
    const float invn = 1.0f / fmaxf(sqrtf(ss), 1e-12f);

    uint2* out64 = reinterpret_cast<uint2*>(out + (size_t)row * Dq);
    uint2 pa, pb;
    pa.x = pack_bf16x2(a.x * invn, a.y * invn);
    pa.y = pack_bf16x2(a.z * invn, a.w * invn);
    pb.x = pack_bf16x2(b.x * invn, b.y * invn);
    pb.y = pack_bf16x2(b.z * invn, b.w * invn);
    out64[lane] = pa;
    out64[lane + 64] = pb;
}

// ---------------------------------------------------------------------------
// 256x256 8-phase GEMM (T1+T2+T3+T4+T5), BK=64, 8 waves (2M x 4N),
// per-wave output 128x64, LDS 2 x (A 32KB + B 32KB) = 128KB double buffer.
// Identical to the round-4 kernel (best: GEMM ~345us) EXCEPT the C-store is
// NONTEMPORAL: the 2.3 TB/s write stream was thrashing the 4MB per-XCD L2
// (8MB of in-flight writeback lines vs ~3MB staging working set), turning
// staging L2-hits into LLC misses. nt stores bypass L2 and keep the A/B
// strips resident.
//
// MFMA operands SWAPPED (A-op = class frag, B-op = emb frag) so each acc
// f32x4 = 4 consecutive class cols of one emb row -> dwordx4 stores.
// Staging rotation per kt (units = 8KB = 64 rows x 64 K):
//   phase 0: ds B(all)+A-quad0; stage A1,A3(kt+1) -> buf[(kt+1)&1]
//   phase 1: ds A-quad1;        stage B0,B1(kt+2) -> buf[kt&1]
//   phase 2: ds A-quad2;        stage B2,B3(kt+2)
//   phase 3: ds A-quad3;        stage A0,A2(kt+2); vmcnt(6); barrier
// ---------------------------------------------------------------------------
__global__ __launch_bounds__(512, 1) void arc_gemm_kernel(
    const unsigned short* __restrict__ A,
    const unsigned short* __restrict__ Bn,
    const int* __restrict__ labels,
    float* __restrict__ out)
{
    extern __shared__ unsigned short lds[];   // 131072 B

    // T1: XCD-aware bijective swizzle (3128 = 8 * 391 exact)
    const int cpx = (int)gridDim.x >> 3;
    const int bid = ((int)blockIdx.x & 7) * cpx + ((int)blockIdx.x >> 3);
    const int tm = bid & 7;          // 8 m-tiles share one B-strip per XCD
    const int tn = bid >> 3;
    const int m0 = tm * 256, n0 = tn * 256;

    const int t = threadIdx.x;
    const int w = t >> 6, lane = t & 63;
    const int wr = (w >> 2) * 128;   // wave M (emb) origin
    const int wc = (w & 3) * 64;     // wave N (class) origin
    const int fr = lane & 15, kg = lane >> 4;
    const int s7 = fr & 7;
    const int c0 = (kg ^ s7) * 8;          // swizzled chunk, ks=0 (elems)
    const int c1 = ((4 + kg) ^ s7) * 8;    // ks=1

    // staging: thread t covers row trow of each 64-row unit, swizzled src col
    const int trow = t >> 3;
    const int tch = ((t & 7) ^ (trow & 7)) * 8;
    const unsigned short* gA = A  + (size_t)(m0 + trow) * Dq + tch;
    const unsigned short* gB = Bn + (size_t)(n0 + trow) * Dq + tch;
    const int dstA = trow * 64 + (t & 7) * 8;   // linear LDS dest (= lane*16 B)

#define STAGE_A(buf, u, kts) gload_lds16(gA + (size_t)(u) * 64 * Dq + (size_t)(kts) * 64, \
                                         &lds[(buf) * 32768 + (u) * 4096 + dstA])
#define STAGE_B(buf, u, kts) gload_lds16(gB + (size_t)(u) * 64 * Dq + (size_t)(kts) * 64, \
                                         &lds[(buf) * 32768 + 16384 + (u) * 4096 + dstA])
#define BARRIER() do { __builtin_amdgcn_sched_barrier(0); __builtin_amdgcn_s_barrier(); } while (0)

    f32x4 acc[8][4];
    #pragma unroll
    for (int i = 0; i < 8; ++i)
        #pragma unroll
        for (int j = 0; j < 4; ++j) acc[i][j] = {0.f, 0.f, 0.f, 0.f};

    // Prologue: K0 complete (8 units) + K1 partial (B0-3, A0, A2)
    STAGE_A(0, 0, 0); STAGE_A(0, 1, 0); STAGE_A(0, 2, 0); STAGE_A(0, 3, 0);
    STAGE_B(0, 0, 0); STAGE_B(0, 1, 0); STAGE_B(0, 2, 0); STAGE_B(0, 3, 0);
    STAGE_B(1, 0, 1); STAGE_B(1, 1, 1); STAGE_B(1, 2, 1); STAGE_B(1, 3, 1);
    STAGE_A(1, 0, 1); STAGE_A(1, 2, 1);
    asm volatile("s_waitcnt vmcnt(6)" ::: "memory");
    __builtin_amdgcn_s_barrier();

    const int arow = (wr + fr) * 64;
    const int brow = 16384 + (wc + fr) * 64;

#define LDA(q) do { \
    _Pragma("unroll") for (int m2 = 0; m2 < 2; ++m2) { \
        afr[m2][0] = *reinterpret_cast<const bf16x8*>(&lds[cbo + arow + ((q) * 32 + m2 * 16) * 64 + c0]); \
        afr[m2][1] = *reinterpret_cast<const bf16x8*>(&lds[cbo + arow + ((q) * 32 + m2 * 16) * 64 + c1]); } \
} while (0)
#define LDB() do { \
    _Pragma("unroll") for (int ni = 0; ni < 4; ++ni) { \
        bfr[ni][0] = *reinterpret_cast<const bf16x8*>(&lds[cbo + brow + ni * 1024 + c0]); \
        bfr[ni][1] = *reinterpret_cast<const bf16x8*>(&lds[cbo + brow + ni * 1024 + c1]); } \
} while (0)
// Operands swapped: A-operand = class frag (bfr), B-operand = emb frag (afr).
#define MFMA_QUAD(q) do { \
    __builtin_amdgcn_s_setprio(1); \
    _Pragma("unroll") for (int ks = 0; ks < 2; ++ks) \
    _Pragma("unroll") for (int m2 = 0; m2 < 2; ++m2) \
    _Pragma("unroll") for (int ni = 0; ni < 4; ++ni) \
        acc[2 * (q) + m2][ni] = __builtin_amdgcn_mfma_f32_16x16x32_bf16( \
            bfr[ni][ks], afr[m2][ks], acc[2 * (q) + m2][ni], 0, 0, 0); \
    __builtin_amdgcn_s_setprio(0); \
} while (0)

    #pragma unroll
    for (int kt = 0; kt < 8; ++kt) {
        const int cb = kt & 1, nb = cb ^ 1;
        const int cbo = cb * 32768;
        bf16x8 bfr[4][2];
        {
            bf16x8 afr[2][2];
            // ---- phase 0: ds B(all) + A quad0; stage A1,A3(kt+1)
            LDB(); LDA(0);
            if (kt < 7) { STAGE_A(nb, 1, kt + 1); STAGE_A(nb, 3, kt + 1); }
            BARRIER();
            MFMA_QUAD(0);
            BARRIER();
            // ---- phase 1: A quad1; stage B0,B1(kt+2)
            LDA(1);
            if (kt < 6) { STAGE_B(cb, 0, kt + 2); STAGE_B(cb, 1, kt + 2); }
            BARRIER();
            MFMA_QUAD(1);
            BARRIER();
            // ---- phase 2: A quad2; stage B2,B3(kt+2)
            LDA(2);
            if (kt < 6) { STAGE_B(cb, 2, kt + 2); STAGE_B(cb, 3, kt + 2); }
            BARRIER();
            MFMA_QUAD(2);
            BARRIER();
            // ---- phase 3: A quad3; stage A0,A2(kt+2); counted vmcnt gate
            LDA(3);
            if (kt < 6) { STAGE_A(cb, 0, kt + 2); STAGE_A(cb, 2, kt + 2); }
            BARRIER();
            MFMA_QUAD(3);
            if (kt < 6) asm volatile("s_waitcnt vmcnt(6)" ::: "memory");
            else        asm volatile("s_waitcnt vmcnt(0)" ::: "memory");
            BARRIER();
        }
    }

    // Epilogue (swapped-operand D mapping):
    //   emb row   = m0 + wr + mi*16 + fr
    //   class col = n0 + wc + ni*16 + kg*4 + reg  -> f32x4 = 4 consecutive cols
    // NONTEMPORAL stores: bypass L2 so the write stream doesn't evict the
    // A/B staging strips of concurrently-running blocks on this XCD.
    const int ccol0 = wc + kg * 4;
    #pragma unroll
    for (int mi = 0; mi < 8; ++mi) {
        const int grow = m0 + wr + mi * 16 + fr;
        const int lab = labels[grow];
        float* orow = out + (size_t)grow * Cq + n0;
        #pragma unroll
        for (int ni = 0; ni < 4; ++ni) {
            const int col0 = ccol0 + ni * 16;
            const int gcol0 = n0 + col0;
            if (gcol0 >= Cq) continue;   // whole vector in padding (both %4==0)
            f32x4 v = acc[mi][ni];
            #pragma unroll
            for (int r = 0; r < 4; ++r) {
                if (gcol0 + r == lab) {
                    float c = v[r];
                    float sine = sqrtf(fmaxf(1.0f - c * c, 0.0f));
                    float phi = c * COS_M - sine * SIN_M;
                    v[r] = (c > THR) ? phi : (c - MM);
                }
            }
            v *= SCALE;
            __builtin_nontemporal_store(v, reinterpret_cast<f32x4*>(orow + col0));
        }
    }
#undef STAGE_A
#undef STAGE_B
#undef BARRIER
#undef LDA
#undef LDB
#undef MFMA_QUAD
}

extern "C" void kernel_launch(void* const* d_in, const int* in_sizes, int n_in,
                              void* d_out, int out_size, void* d_ws, size_t ws_size,
                              hipStream_t stream)
{
    const float* emb    = (const float*)d_in[0];
    const int*   labels = (const int*)d_in[1];
    const float* weight = (const float*)d_in[2];
    float* out = (float*)d_out;

    unsigned short* Abf = (unsigned short*)d_ws;             // 2 MB
    unsigned short* Bbf = Abf + (size_t)Bq * Dq;             // 102.5 MB

    normalize_rows_kernel<<<Bq / 4, 256, 0, stream>>>(emb, Abf, Bq);
    normalize_rows_kernel<<<NPAD / 4, 256, 0, stream>>>(weight, Bbf, Cq);
    arc_gemm_kernel<<<8 * (NPAD / 256), 512, 131072, stream>>>(Abf, Bbf, labels, out);
}

// Round 8
// 368.288 us; speedup vs baseline: 4.6477x; 1.0397x over previous
//
#include <hip/hip_runtime.h>
#include <hip/hip_bf16.h>
#include <math.h>

// Problem constants (B=2048, D=512, C=100000)
constexpr int Bq = 2048;
constexpr int Dq = 512;
constexpr int Cq = 100000;
constexpr int NPAD = 100096;     // 782 * 128

constexpr float SCALE = 64.0f;
constexpr float COS_M = 0.8775825618903728f;   // cos(0.5)
constexpr float SIN_M = 0.479425538604203f;    // sin(0.5)
constexpr float THR   = -0.8775825618903728f;  // cos(pi - 0.5)
constexpr float MM    = 0.2397127693021015f;   // sin(pi - 0.5) * 0.5

typedef __attribute__((ext_vector_type(8))) __bf16 bf16x8;
typedef __attribute__((ext_vector_type(4))) float f32x4;

typedef const __attribute__((address_space(1))) unsigned int guint;
typedef __attribute__((address_space(3))) unsigned int suint;

__device__ __forceinline__ void gload_lds16(const unsigned short* g, unsigned short* lds)
{
    __builtin_amdgcn_global_load_lds((guint*)g, (suint*)lds, 16, 0, 0);
}

__device__ __forceinline__ unsigned int pack_bf16x2(float lo, float hi)
{
    __hip_bfloat16 h0 = __float2bfloat16(lo);
    __hip_bfloat16 h1 = __float2bfloat16(hi);
    return ((unsigned int)(*(unsigned short*)&h1) << 16) |
           (unsigned int)(*(unsigned short*)&h0);
}

// ---------------------------------------------------------------------------
// Row L2-normalize fp32 [*][512] -> bf16, wave-per-row, float4 loads,
// pure shuffle reduce. 4 rows per 256-thread block. Pad rows write zeros.
// ---------------------------------------------------------------------------
__global__ __launch_bounds__(256) void normalize_rows_kernel(
    const float* __restrict__ in, unsigned short* __restrict__ out, int nrows)
{
    const int w = threadIdx.x >> 6, lane = threadIdx.x & 63;
    const int row = blockIdx.x * 4 + w;
    float4 a = {0.f, 0.f, 0.f, 0.f}, b = a;
    if (row < nrows) {
        const float4* src = reinterpret_cast<const float4*>(in + (size_t)row * Dq);
        a = src[lane];
        b = src[lane + 64];
    }
    float ss = a.x * a.x + a.y * a.y + a.z * a.z + a.w * a.w
             + b.x * b.x + b.y * b.y + b.z * b.z + b.w * b.w;
    #pragma unroll
    for (int off = 32; off > 0; off >>= 1) ss += __shfl_down(ss, off);
    ss = __shfl(ss, 0);
    const float invn = 1.0f / fmaxf(sqrtf(ss), 1e-12f);

    uint2* out64 = reinterpret_cast<uint2*>(out + (size_t)row * Dq);
    uint2 pa, pb;
    pa.x = pack_bf16x2(a.x * invn, a.y * invn);
    pa.y = pack_bf16x2(a.z * invn, a.w * invn);
    pb.x = pack_bf16x2(b.x * invn, b.y * invn);
    pb.y = pack_bf16x2(b.z * invn, b.w * invn);
    out64[lane] = pa;
    out64[lane + 64] = pb;
}

// ---------------------------------------------------------------------------
// 128x128 8-phase GEMM, BK=64, 4 waves (2M x 2N, 64x64 per wave),
// LDS 2 x (A 16KB + B 16KB) = 64KB double buffer -> 2 BLOCKS/CU (LDS-bound;
// launch_bounds(256,2) keeps VGPR cap at 256, no spill). Same R7 schedule:
// counted-vmcnt rotation, T1 XCD swizzle, T2 involution LDS swizzle, T5
// setprio, swapped-operand MFMA, nontemporal C-stores. The second resident
// block absorbs gate stalls / epilogue bursts of its sibling (round-7's
// residual: 1 block/CU exposed every staging-latency bubble).
//
// Staging rotation per kt (slabs = 4KB = 32 rows x 64 K; A0..A3, B0..B3):
//   phase 0: ds B(all)+A-quad0; stage A1,A3(kt+1) -> buf[(kt+1)&1]
//   phase 1: ds A-quad1;        stage B0,B1(kt+2) -> buf[kt&1]  (B dead after ph0)
//   phase 2: ds A-quad2;        stage B2,B3(kt+2)
//   phase 3: ds A-quad3;        stage A0,A2(kt+2)  (rows 0-31/64-95, disjoint
//            from quad3 reads rows 48-63/112-127); vmcnt(6); barrier
// Ledger: at each gate the 6 newest in-flight loads are exactly the kt+2
// partials; kt+1 has fully landed.
// ---------------------------------------------------------------------------
__global__ __launch_bounds__(256, 2) void arc_gemm_kernel(
    const unsigned short* __restrict__ A,
    const unsigned short* __restrict__ Bn,
    const int* __restrict__ labels,
    float* __restrict__ out)
{
    __shared__ unsigned short lds[32768];   // 64 KB: 2 x (A 16KB | B 16KB)

    // T1: XCD-aware bijective swizzle (12512 = 8 * 1564 exact)
    const int cpx = (int)gridDim.x >> 3;
    const int bid = ((int)blockIdx.x & 7) * cpx + ((int)blockIdx.x >> 3);
    const int tm = bid & 15;         // 16 m-tiles share one B-strip per XCD
    const int tn = bid >> 4;
    const int m0 = tm * 128, n0 = tn * 128;

    const int t = threadIdx.x;
    const int w = t >> 6, lane = t & 63;
    const int wr = (w >> 1) * 64;    // wave M (emb) origin
    const int wc = (w & 1) * 64;     // wave N (class) origin
    const int fr = lane & 15, kg = lane >> 4;
    const int s7 = fr & 7;
    const int c0 = (kg ^ s7) * 8;          // swizzled chunk, ks=0 (elems)
    const int c1 = ((4 + kg) ^ s7) * 8;    // ks=1

    // staging: thread t covers row trow (0..31) of a 32-row slab, swizzled col
    const int trow = t >> 3;
    const int tch = ((t & 7) ^ (trow & 7)) * 8;
    const unsigned short* gA = A  + (size_t)(m0 + trow) * Dq + tch;
    const unsigned short* gB = Bn + (size_t)(n0 + trow) * Dq + tch;
    const int dstA = trow * 64 + (t & 7) * 8;   // linear LDS dest (= tid*16 B)

#define STAGE_A(buf, s, kts) gload_lds16(gA + (size_t)(s) * 32 * Dq + (size_t)(kts) * 64, \
                                         &lds[(buf) * 16384 + (s) * 2048 + dstA])
#define STAGE_B(buf, s, kts) gload_lds16(gB + (size_t)(s) * 32 * Dq + (size_t)(kts) * 64, \
                                         &lds[(buf) * 16384 + 8192 + (s) * 2048 + dstA])
#define BARRIER() do { __builtin_amdgcn_sched_barrier(0); __builtin_amdgcn_s_barrier(); } while (0)

    f32x4 acc[4][4];
    #pragma unroll
    for (int i = 0; i < 4; ++i)
        #pragma unroll
        for (int j = 0; j < 4; ++j) acc[i][j] = {0.f, 0.f, 0.f, 0.f};

    // Prologue: K0 complete (8 slabs) + K1 partial (B0-3, A0, A2)
    STAGE_A(0, 0, 0); STAGE_A(0, 1, 0); STAGE_A(0, 2, 0); STAGE_A(0, 3, 0);
    STAGE_B(0, 0, 0); STAGE_B(0, 1, 0); STAGE_B(0, 2, 0); STAGE_B(0, 3, 0);
    STAGE_B(1, 0, 1); STAGE_B(1, 1, 1); STAGE_B(1, 2, 1); STAGE_B(1, 3, 1);
    STAGE_A(1, 0, 1); STAGE_A(1, 2, 1);
    asm volatile("s_waitcnt vmcnt(6)" ::: "memory");
    __builtin_amdgcn_s_barrier();

    const int arow = (wr + fr) * 64;
    const int brow = 8192 + (wc + fr) * 64;

#define LDA(q) do { \
    afr[0] = *reinterpret_cast<const bf16x8*>(&lds[cbo + arow + (q) * 1024 + c0]); \
    afr[1] = *reinterpret_cast<const bf16x8*>(&lds[cbo + arow + (q) * 1024 + c1]); \
} while (0)
#define LDB() do { \
    _Pragma("unroll") for (int ni = 0; ni < 4; ++ni) { \
        bfr[ni][0] = *reinterpret_cast<const bf16x8*>(&lds[cbo + brow + ni * 1024 + c0]); \
        bfr[ni][1] = *reinterpret_cast<const bf16x8*>(&lds[cbo + brow + ni * 1024 + c1]); } \
} while (0)
// Operands swapped: A-operand = class frag (bfr), B-operand = emb frag (afr).
#define MFMA_QUAD(q) do { \
    __builtin_amdgcn_s_setprio(1); \
    _Pragma("unroll") for (int ks = 0; ks < 2; ++ks) \
    _Pragma("unroll") for (int ni = 0; ni < 4; ++ni) \
        acc[(q)][ni] = __builtin_amdgcn_mfma_f32_16x16x32_bf16( \
            bfr[ni][ks], afr[ks], acc[(q)][ni], 0, 0, 0); \
    __builtin_amdgcn_s_setprio(0); \
} while (0)

    #pragma unroll
    for (int kt = 0; kt < 8; ++kt) {
        const int cb = kt & 1, nb = cb ^ 1;
        const int cbo = cb * 16384;
        bf16x8 bfr[4][2];
        bf16x8 afr[2];
        // ---- phase 0: ds B(all) + A quad0; stage A1,A3(kt+1)
        LDB(); LDA(0);
        if (kt < 7) { STAGE_A(nb, 1, kt + 1); STAGE_A(nb, 3, kt + 1); }
        BARRIER();
        MFMA_QUAD(0);
        BARRIER();
        // ---- phase 1: A quad1; stage B0,B1(kt+2)
        LDA(1);
        if (kt < 6) { STAGE_B(cb, 0, kt + 2); STAGE_B(cb, 1, kt + 2); }
        BARRIER();
        MFMA_QUAD(1);
        BARRIER();
        // ---- phase 2: A quad2; stage B2,B3(kt+2)
        LDA(2);
        if (kt < 6) { STAGE_B(cb, 2, kt + 2); STAGE_B(cb, 3, kt + 2); }
        BARRIER();
        MFMA_QUAD(2);
        BARRIER();
        // ---- phase 3: A quad3; stage A0,A2(kt+2); counted vmcnt gate
        LDA(3);
        if (kt < 6) { STAGE_A(cb, 0, kt + 2); STAGE_A(cb, 2, kt + 2); }
        BARRIER();
        MFMA_QUAD(3);
        if (kt < 6) asm volatile("s_waitcnt vmcnt(6)" ::: "memory");
        else        asm volatile("s_waitcnt vmcnt(0)" ::: "memory");
        BARRIER();
    }

    // Epilogue (swapped-operand D mapping):
    //   emb row   = m0 + wr + mi*16 + fr
    //   class col = n0 + wc + ni*16 + kg*4 + reg  -> f32x4 = 4 consecutive cols
    // Nontemporal: keep the write stream out of the XCD L2.
    const int ccol0 = wc + kg * 4;
    #pragma unroll
    for (int mi = 0; mi < 4; ++mi) {
        const int grow = m0 + wr + mi * 16 + fr;
        const int lab = labels[grow];
        float* orow = out + (size_t)grow * Cq + n0;
        #pragma unroll
        for (int ni = 0; ni < 4; ++ni) {
            const int col0 = ccol0 + ni * 16;
            const int gcol0 = n0 + col0;
            if (gcol0 >= Cq) continue;   // whole vector in padding (both %4==0)
            f32x4 v = acc[mi][ni];
            #pragma unroll
            for (int r = 0; r < 4; ++r) {
                if (gcol0 + r == lab) {
                    float c = v[r];
                    float sine = sqrtf(fmaxf(1.0f - c * c, 0.0f));
                    float phi = c * COS_M - sine * SIN_M;
                    v[r] = (c > THR) ? phi : (c - MM);
                }
            }
            v *= SCALE;
            __builtin_nontemporal_store(v, reinterpret_cast<f32x4*>(orow + col0));
        }
    }
#undef STAGE_A
#undef STAGE_B
#undef BARRIER
#undef LDA
#undef LDB
#undef MFMA_QUAD
}

extern "C" void kernel_launch(void* const* d_in, const int* in_sizes, int n_in,
                              void* d_out, int out_size, void* d_ws, size_t ws_size,
                              hipStream_t stream)
{
    const float* emb    = (const float*)d_in[0];
    const int*   labels = (const int*)d_in[1];
    const float* weight = (const float*)d_in[2];
    float* out = (float*)d_out;

    unsigned short* Abf = (unsigned short*)d_ws;             // 2 MB
    unsigned short* Bbf = Abf + (size_t)Bq * Dq;             // 102.5 MB

    normalize_rows_kernel<<<Bq / 4, 256, 0, stream>>>(emb, Abf, Bq);
    normalize_rows_kernel<<<NPAD / 4, 256, 0, stream>>>(weight, Bbf, Cq);
    arc_gemm_kernel<<<16 * (NPAD / 128), 256, 0, stream>>>(Abf, Bbf, labels, out);
}

// Round 9
// 325.611 us; speedup vs baseline: 5.2568x; 1.1311x over previous
//
#include <hip/hip_runtime.h>
#include <hip/hip_bf16.h>
#include <math.h>

// Problem constants (B=2048, D=512, C=100000)
constexpr int Bq = 2048;
constexpr int Dq = 512;
constexpr int Cq = 100000;
constexpr int NPAD = 100096;     // 782 * 128

constexpr float SCALE = 64.0f;
constexpr float COS_M = 0.8775825618903728f;   // cos(0.5)
constexpr float SIN_M = 0.479425538604203f;    // sin(0.5)
constexpr float THR   = -0.8775825618903728f;  // cos(pi - 0.5)
constexpr float MM    = 0.2397127693021015f;   // sin(pi - 0.5) * 0.5

typedef __attribute__((ext_vector_type(8))) __bf16 bf16x8;
typedef __attribute__((ext_vector_type(4))) float f32x4;

typedef const __attribute__((address_space(1))) unsigned int guint;
typedef __attribute__((address_space(3))) unsigned int suint;

__device__ __forceinline__ void gload_lds16(const unsigned short* g, unsigned short* lds)
{
    __builtin_amdgcn_global_load_lds((guint*)g, (suint*)lds, 16, 0, 0);
}

__device__ __forceinline__ unsigned int pack_bf16x2(float lo, float hi)
{
    __hip_bfloat16 h0 = __float2bfloat16(lo);
    __hip_bfloat16 h1 = __float2bfloat16(hi);
    return ((unsigned int)(*(unsigned short*)&h1) << 16) |
           (unsigned int)(*(unsigned short*)&h0);
}

// ---------------------------------------------------------------------------
// Row L2-normalize fp32 [*][512] -> bf16, wave-per-row, float4 loads,
// pure shuffle reduce. 4 rows per 256-thread block. Pad rows write zeros.
// ---------------------------------------------------------------------------
__global__ __launch_bounds__(256) void normalize_rows_kernel(
    const float* __restrict__ in, unsigned short* __restrict__ out, int nrows)
{
    const int w = threadIdx.x >> 6, lane = threadIdx.x & 63;
    const int row = blockIdx.x * 4 + w;
    float4 a = {0.f, 0.f, 0.f, 0.f}, b = a;
    if (row < nrows) {
        const float4* src = reinterpret_cast<const float4*>(in + (size_t)row * Dq);
        a = src[lane];
        b = src[lane + 64];
    }
    float ss = a.x * a.x + a.y * a.y + a.z * a.z + a.w * a.w
             + b.x * b.x + b.y * b.y + b.z * b.z + b.w * b.w;
    #pragma unroll
    for (int off = 32; off > 0; off >>= 1) ss += __shfl_down(ss, off);
    ss = __shfl(ss, 0);
    const float invn = 1.0f / fmaxf(sqrtf(ss), 1e-12f);

    uint2* out64 = reinterpret_cast<uint2*>(out + (size_t)row * Dq);
    uint2 pa, pb;
    pa.x = pack_bf16x2(a.x * invn, a.y * invn);
    pa.y = pack_bf16x2(a.z * invn, a.w * invn);
    pb.x = pack_bf16x2(b.x * invn, b.y * invn);
    pb.y = pack_bf16x2(b.z * invn, b.w * invn);
    out64[lane] = pa;
    out64[lane + 64] = pb;
}

// ---------------------------------------------------------------------------
// 128x128 8-phase GEMM, BK=64, 4 waves (2M x 2N), LDS 64KB double buffer,
// 2 blocks/CU. Counted-vmcnt rotation, T1 XCD swizzle, T2 involution LDS
// swizzle, T5 setprio, swapped-operand MFMA, nt C-stores.
//
// ROUND 9 CHANGE (epilogue only): the old per-fragment nt dwordx4 stores
// wrote 16 rows x 64B per instruction -> partial 128B lines -> WRITE_SIZE
// 1.089 GB vs 819 MB ideal (+33% HBM write amplification). Now the C-tile
// goes acc -> LDS [128][132] fp32 (pad 132 -> uniform bank spread) -> read
// back 2 rows x 512B per instruction -> nt stores are fully line-aligned
// 1KB-per-instruction bursts (the fillBuffer pattern: 0% inflation,
// 6.7 TB/s). LDS 67.6 KB -> still 2 blocks/CU.
//
// Staging rotation per kt (slabs = 4KB = 32 rows x 64 K; A0..A3, B0..B3):
//   phase 0: ds B(all)+A-quad0; stage A1,A3(kt+1) -> buf[(kt+1)&1]
//   phase 1: ds A-quad1;        stage B0,B1(kt+2) -> buf[kt&1]
//   phase 2: ds A-quad2;        stage B2,B3(kt+2)
//   phase 3: ds A-quad3;        stage A0,A2(kt+2); vmcnt(6); barrier
// ---------------------------------------------------------------------------
__global__ __launch_bounds__(256, 2) void arc_gemm_kernel(
    const unsigned short* __restrict__ A,
    const unsigned short* __restrict__ Bn,
    const int* __restrict__ labels,
    float* __restrict__ out)
{
    extern __shared__ unsigned short lds[];   // 67584 B (K-loop uses 65536)

    // T1: XCD-aware bijective swizzle (12512 = 8 * 1564 exact)
    const int cpx = (int)gridDim.x >> 3;
    const int bid = ((int)blockIdx.x & 7) * cpx + ((int)blockIdx.x >> 3);
    const int tm = bid & 15;         // 16 m-tiles share one B-strip per XCD
    const int tn = bid >> 4;
    const int m0 = tm * 128, n0 = tn * 128;

    const int t = threadIdx.x;
    const int w = t >> 6, lane = t & 63;
    const int wr = (w >> 1) * 64;    // wave M (emb) origin
    const int wc = (w & 1) * 64;     // wave N (class) origin
    const int fr = lane & 15, kg = lane >> 4;
    const int s7 = fr & 7;
    const int c0 = (kg ^ s7) * 8;          // swizzled chunk, ks=0 (elems)
    const int c1 = ((4 + kg) ^ s7) * 8;    // ks=1

    // staging: thread t covers row trow (0..31) of a 32-row slab, swizzled col
    const int trow = t >> 3;
    const int tch = ((t & 7) ^ (trow & 7)) * 8;
    const unsigned short* gA = A  + (size_t)(m0 + trow) * Dq + tch;
    const unsigned short* gB = Bn + (size_t)(n0 + trow) * Dq + tch;
    const int dstA = trow * 64 + (t & 7) * 8;   // linear LDS dest (= tid*16 B)

#define STAGE_A(buf, s, kts) gload_lds16(gA + (size_t)(s) * 32 * Dq + (size_t)(kts) * 64, \
                                         &lds[(buf) * 16384 + (s) * 2048 + dstA])
#define STAGE_B(buf, s, kts) gload_lds16(gB + (size_t)(s) * 32 * Dq + (size_t)(kts) * 64, \
                                         &lds[(buf) * 16384 + 8192 + (s) * 2048 + dstA])
#define BARRIER() do { __builtin_amdgcn_sched_barrier(0); __builtin_amdgcn_s_barrier(); } while (0)

    f32x4 acc[4][4];
    #pragma unroll
    for (int i = 0; i < 4; ++i)
        #pragma unroll
        for (int j = 0; j < 4; ++j) acc[i][j] = {0.f, 0.f, 0.f, 0.f};

    // Prologue: K0 complete (8 slabs) + K1 partial (B0-3, A0, A2)
    STAGE_A(0, 0, 0); STAGE_A(0, 1, 0); STAGE_A(0, 2, 0); STAGE_A(0, 3, 0);
    STAGE_B(0, 0, 0); STAGE_B(0, 1, 0); STAGE_B(0, 2, 0); STAGE_B(0, 3, 0);
    STAGE_B(1, 0, 1); STAGE_B(1, 1, 1); STAGE_B(1, 2, 1); STAGE_B(1, 3, 1);
    STAGE_A(1, 0, 1); STAGE_A(1, 2, 1);
    asm volatile("s_waitcnt vmcnt(6)" ::: "memory");
    __builtin_amdgcn_s_barrier();

    const int arow = (wr + fr) * 64;
    const int brow = 8192 + (wc + fr) * 64;

#define LDA(q) do { \
    afr[0] = *reinterpret_cast<const bf16x8*>(&lds[cbo + arow + (q) * 1024 + c0]); \
    afr[1] = *reinterpret_cast<const bf16x8*>(&lds[cbo + arow + (q) * 1024 + c1]); \
} while (0)
#define LDB() do { \
    _Pragma("unroll") for (int ni = 0; ni < 4; ++ni) { \
        bfr[ni][0] = *reinterpret_cast<const bf16x8*>(&lds[cbo + brow + ni * 1024 + c0]); \
        bfr[ni][1] = *reinterpret_cast<const bf16x8*>(&lds[cbo + brow + ni * 1024 + c1]); } \
} while (0)
// Operands swapped: A-operand = class frag (bfr), B-operand = emb frag (afr).
#define MFMA_QUAD(q) do { \
    __builtin_amdgcn_s_setprio(1); \
    _Pragma("unroll") for (int ks = 0; ks < 2; ++ks) \
    _Pragma("unroll") for (int ni = 0; ni < 4; ++ni) \
        acc[(q)][ni] = __builtin_amdgcn_mfma_f32_16x16x32_bf16( \
            bfr[ni][ks], afr[ks], acc[(q)][ni], 0, 0, 0); \
    __builtin_amdgcn_s_setprio(0); \
} while (0)

    #pragma unroll
    for (int kt = 0; kt < 8; ++kt) {
        const int cb = kt & 1, nb = cb ^ 1;
        const int cbo = cb * 16384;
        bf16x8 bfr[4][2];
        bf16x8 afr[2];
        // ---- phase 0: ds B(all) + A quad0; stage A1,A3(kt+1)
        LDB(); LDA(0);
        if (kt < 7) { STAGE_A(nb, 1, kt + 1); STAGE_A(nb, 3, kt + 1); }
        BARRIER();
        MFMA_QUAD(0);
        BARRIER();
        // ---- phase 1: A quad1; stage B0,B1(kt+2)
        LDA(1);
        if (kt < 6) { STAGE_B(cb, 0, kt + 2); STAGE_B(cb, 1, kt + 2); }
        BARRIER();
        MFMA_QUAD(1);
        BARRIER();
        // ---- phase 2: A quad2; stage B2,B3(kt+2)
        LDA(2);
        if (kt < 6) { STAGE_B(cb, 2, kt + 2); STAGE_B(cb, 3, kt + 2); }
        BARRIER();
        MFMA_QUAD(2);
        BARRIER();
        // ---- phase 3: A quad3; stage A0,A2(kt+2); counted vmcnt gate
        LDA(3);
        if (kt < 6) { STAGE_A(cb, 0, kt + 2); STAGE_A(cb, 2, kt + 2); }
        BARRIER();
        MFMA_QUAD(3);
        if (kt < 6) asm volatile("s_waitcnt vmcnt(6)" ::: "memory");
        else        asm volatile("s_waitcnt vmcnt(0)" ::: "memory");
        BARRIER();
    }

    // ---- Epilogue v2: acc -> LDS [128][132] fp32 -> line-aligned nt stores.
    // acc mapping (swapped operands): emb row = wr + mi*16 + fr (block-local),
    // class col = wc + ni*16 + kg*4 + reg. Margin applied in registers first.
    float* lf = reinterpret_cast<float*>(lds);
    #pragma unroll
    for (int mi = 0; mi < 4; ++mi) {
        const int lrow = wr + mi * 16 + fr;
        const int lab = labels[m0 + lrow];
        #pragma unroll
        for (int ni = 0; ni < 4; ++ni) {
            const int col0 = wc + ni * 16 + kg * 4;
            const int gcol0 = n0 + col0;
            f32x4 v = acc[mi][ni];
            #pragma unroll
            for (int r = 0; r < 4; ++r) {
                if (gcol0 + r == lab) {
                    float c = v[r];
                    float sine = sqrtf(fmaxf(1.0f - c * c, 0.0f));
                    float phi = c * COS_M - sine * SIN_M;
                    v[r] = (c > THR) ? phi : (c - MM);
                }
            }
            v *= SCALE;
            *reinterpret_cast<f32x4*>(&lf[lrow * 132 + col0]) = v;
        }
    }
    __syncthreads();
    // read back: instruction covers 2 rows x 512B; nt store = two aligned
    // 512B bursts (full 128B lines). Tail strip: vectors are all-in/all-out.
    const int cc = lane & 31, rh = lane >> 5;
    #pragma unroll
    for (int s = 0; s < 16; ++s) {
        const int lrow = (w * 16 + s) * 2 + rh;
        f32x4 v = *reinterpret_cast<const f32x4*>(&lf[lrow * 132 + cc * 4]);
        const int gcol0 = n0 + cc * 4;
        if (gcol0 < Cq)
            __builtin_nontemporal_store(
                v, reinterpret_cast<f32x4*>(out + (size_t)(m0 + lrow) * Cq + gcol0));
    }
#undef STAGE_A
#undef STAGE_B
#undef BARRIER
#undef LDA
#undef LDB
#undef MFMA_QUAD
}

extern "C" void kernel_launch(void* const* d_in, const int* in_sizes, int n_in,
                              void* d_out, int out_size, void* d_ws, size_t ws_size,
                              hipStream_t stream)
{
    const float* emb    = (const float*)d_in[0];
    const int*   labels = (const int*)d_in[1];
    const float* weight = (const float*)d_in[2];
    float* out = (float*)d_out;

    unsigned short* Abf = (unsigned short*)d_ws;             // 2 MB
    unsigned short* Bbf = Abf + (size_t)Bq * Dq;             // 102.5 MB

    normalize_rows_kernel<<<Bq / 4, 256, 0, stream>>>(emb, Abf, Bq);
    normalize_rows_kernel<<<NPAD / 4, 256, 0, stream>>>(weight, Bbf, Cq);
    arc_gemm_kernel<<<16 * (NPAD / 128), 256, 67584, stream>>>(Abf, Bbf, labels, out);
}

// Round 11
// 325.189 us; speedup vs baseline: 5.2636x; 1.0013x over previous
//
#include <hip/hip_runtime.h>
#include <hip/hip_bf16.h>
#include <math.h>

// Problem constants (B=2048, D=512, C=100000)
constexpr int Bq = 2048;
constexpr int Dq = 512;
constexpr int Cq = 100000;
constexpr int NPAD = 100096;     // 782 * 128

constexpr float SCALE = 64.0f;
constexpr float COS_M = 0.8775825618903728f;   // cos(0.5)
constexpr float SIN_M = 0.479425538604203f;    // sin(0.5)
constexpr float THR   = -0.8775825618903728f;  // cos(pi - 0.5)
constexpr float MM    = 0.2397127693021015f;   // sin(pi - 0.5) * 0.5

typedef __attribute__((ext_vector_type(8))) __bf16 bf16x8;
typedef __attribute__((ext_vector_type(4))) float f32x4;

typedef const __attribute__((address_space(1))) unsigned int guint;
typedef __attribute__((address_space(3))) unsigned int suint;

__device__ __forceinline__ void gload_lds16(const unsigned short* g, unsigned short* lds)
{
    __builtin_amdgcn_global_load_lds((guint*)g, (suint*)lds, 16, 0, 0);
}

__device__ __forceinline__ unsigned int pack_bf16x2(float lo, float hi)
{
    __hip_bfloat16 h0 = __float2bfloat16(lo);
    __hip_bfloat16 h1 = __float2bfloat16(hi);
    return ((unsigned int)(*(unsigned short*)&h1) << 16) |
           (unsigned int)(*(unsigned short*)&h0);
}

// ---------------------------------------------------------------------------
// Row L2-normalize fp32 [*][512] -> bf16, wave-per-row, float4 loads,
// pure shuffle reduce. 4 rows per 256-thread block. Pad rows write zeros.
// ---------------------------------------------------------------------------
__global__ __launch_bounds__(256) void normalize_rows_kernel(
    const float* __restrict__ in, unsigned short* __restrict__ out, int nrows)
{
    const int w = threadIdx.x >> 6, lane = threadIdx.x & 63;
    const int row = blockIdx.x * 4 + w;
    float4 a = {0.f, 0.f, 0.f, 0.f}, b = a;
    if (row < nrows) {
        const float4* src = reinterpret_cast<const float4*>(in + (size_t)row * Dq);
        a = src[lane];
        b = src[lane + 64];
    }
    float ss = a.x * a.x + a.y * a.y + a.z * a.z + a.w * a.w
             + b.x * b.x + b.y * b.y + b.z * b.z + b.w * b.w;
    #pragma unroll
    for (int off = 32; off > 0; off >>= 1) ss += __shfl_down(ss, off);
    ss = __shfl(ss, 0);
    const float invn = 1.0f / fmaxf(sqrtf(ss), 1e-12f);

    uint2* out64 = reinterpret_cast<uint2*>(out + (size_t)row * Dq);
    uint2 pa, pb;
    pa.x = pack_bf16x2(a.x * invn, a.y * invn);
    pa.y = pack_bf16x2(a.z * invn, a.w * invn);
    pb.x = pack_bf16x2(b.x * invn, b.y * invn);
    pb.y = pack_bf16x2(b.z * invn, b.w * invn);
    out64[lane] = pa;
    out64[lane + 64] = pb;
}

// ---------------------------------------------------------------------------
// 128x128 GEMM, BK=64, 4 waves (2M x 2N), LDS 64KB double buffer, 2 blocks/CU.
// 2 phases/kt, 16-MFMA clusters, 4 barriers/kt, counted-vmcnt ledger.
//
// SLAB/QUAD MAP (the round-10 bug): A-quad q is the wave-interleaved 16-row
// m-chunk {wr + q*16 + fr}, wr in {0,64}; A-slab s is contiguous rows
// [32s, 32s+32). Quads 0,1 touch slabs {0,2}; quads 2,3 touch slabs {1,3}.
// Race-audited rotation:
//   Phase A: ds B(all)+quads 0,1 [12 b128]; stage A1,A3(kt+1)->nb (nb is
//            unread during all of kt); barrier; MFMA quads 0+1; barrier.
//   Phase B: ds quads 2,3 (slabs 1,3); stage B0-3,A0,A2(kt+2)->cb (B and
//            slabs 0,2 are read ONLY in phase A, whose ds_reads lgkm-drain
//            before each wave's phase-A MFMA -> complete block-wide at the
//            post-A barrier; disjoint from phase-B's own reads);
//            barrier; MFMA quads 2+3; vmcnt(6) gate; barrier.
// Ledger: at each kt gate exactly the 6 kt+2 partials (B0-3,A0,A2) remain
// in flight; all of kt+1 has landed (partials from kt-1 phase B, A1,A3
// from kt phase A — both older than the gate's 6).
// T1 XCD swizzle, T2 involution LDS swizzle, T5 setprio, swapped-operand
// MFMA, LDS-transposed line-aligned nt epilogue (WRITE_SIZE = nominal).
// ---------------------------------------------------------------------------
__global__ __launch_bounds__(256, 2) void arc_gemm_kernel(
    const unsigned short* __restrict__ A,
    const unsigned short* __restrict__ Bn,
    const int* __restrict__ labels,
    float* __restrict__ out)
{
    extern __shared__ unsigned short lds[];   // 67584 B (K-loop uses 65536)

    // T1: XCD-aware bijective swizzle (12512 = 8 * 1564 exact)
    const int cpx = (int)gridDim.x >> 3;
    const int bid = ((int)blockIdx.x & 7) * cpx + ((int)blockIdx.x >> 3);
    const int tm = bid & 15;         // 16 m-tiles share one B-strip per XCD
    const int tn = bid >> 4;
    const int m0 = tm * 128, n0 = tn * 128;

    const int t = threadIdx.x;
    const int w = t >> 6, lane = t & 63;
    const int wr = (w >> 1) * 64;    // wave M (emb) origin
    const int wc = (w & 1) * 64;     // wave N (class) origin
    const int fr = lane & 15, kg = lane >> 4;
    const int s7 = fr & 7;
    const int c0 = (kg ^ s7) * 8;          // swizzled chunk, ks=0 (elems)
    const int c1 = ((4 + kg) ^ s7) * 8;    // ks=1

    // staging: thread t covers row trow (0..31) of a 32-row slab, swizzled col
    const int trow = t >> 3;
    const int tch = ((t & 7) ^ (trow & 7)) * 8;
    const unsigned short* gA = A  + (size_t)(m0 + trow) * Dq + tch;
    const unsigned short* gB = Bn + (size_t)(n0 + trow) * Dq + tch;
    const int dstA = trow * 64 + (t & 7) * 8;   // linear LDS dest (= tid*16 B)

#define STAGE_A(buf, s, kts) gload_lds16(gA + (size_t)(s) * 32 * Dq + (size_t)(kts) * 64, \
                                         &lds[(buf) * 16384 + (s) * 2048 + dstA])
#define STAGE_B(buf, s, kts) gload_lds16(gB + (size_t)(s) * 32 * Dq + (size_t)(kts) * 64, \
                                         &lds[(buf) * 16384 + 8192 + (s) * 2048 + dstA])
#define BARRIER() do { __builtin_amdgcn_sched_barrier(0); __builtin_amdgcn_s_barrier(); } while (0)

    f32x4 acc[4][4];
    #pragma unroll
    for (int i = 0; i < 4; ++i)
        #pragma unroll
        for (int j = 0; j < 4; ++j) acc[i][j] = {0.f, 0.f, 0.f, 0.f};

    // Prologue: K0 complete (8 slabs) + K1 partial (B0-3, A0, A2)
    STAGE_A(0, 0, 0); STAGE_A(0, 1, 0); STAGE_A(0, 2, 0); STAGE_A(0, 3, 0);
    STAGE_B(0, 0, 0); STAGE_B(0, 1, 0); STAGE_B(0, 2, 0); STAGE_B(0, 3, 0);
    STAGE_B(1, 0, 1); STAGE_B(1, 1, 1); STAGE_B(1, 2, 1); STAGE_B(1, 3, 1);
    STAGE_A(1, 0, 1); STAGE_A(1, 2, 1);
    asm volatile("s_waitcnt vmcnt(6)" ::: "memory");
    __builtin_amdgcn_s_barrier();

    const int arow = (wr + fr) * 64;
    const int brow = 8192 + (wc + fr) * 64;

#define LDAQ(dst, q) do { \
    dst[0] = *reinterpret_cast<const bf16x8*>(&lds[cbo + arow + (q) * 1024 + c0]); \
    dst[1] = *reinterpret_cast<const bf16x8*>(&lds[cbo + arow + (q) * 1024 + c1]); \
} while (0)
#define LDB() do { \
    _Pragma("unroll") for (int ni = 0; ni < 4; ++ni) { \
        bfr[ni][0] = *reinterpret_cast<const bf16x8*>(&lds[cbo + brow + ni * 1024 + c0]); \
        bfr[ni][1] = *reinterpret_cast<const bf16x8*>(&lds[cbo + brow + ni * 1024 + c1]); } \
} while (0)
// Operands swapped: A-operand = class frag (bfr), B-operand = emb frag.
#define MFMA_PAIR(q0, a0, q1, a1) do { \
    __builtin_amdgcn_s_setprio(1); \
    _Pragma("unroll") for (int ks = 0; ks < 2; ++ks) \
    _Pragma("unroll") for (int ni = 0; ni < 4; ++ni) { \
        acc[(q0)][ni] = __builtin_amdgcn_mfma_f32_16x16x32_bf16( \
            bfr[ni][ks], a0[ks], acc[(q0)][ni], 0, 0, 0); \
        acc[(q1)][ni] = __builtin_amdgcn_mfma_f32_16x16x32_bf16( \
            bfr[ni][ks], a1[ks], acc[(q1)][ni], 0, 0, 0); } \
    __builtin_amdgcn_s_setprio(0); \
} while (0)

    #pragma unroll
    for (int kt = 0; kt < 8; ++kt) {
        const int cb = kt & 1, nb = cb ^ 1;
        const int cbo = cb * 16384;
        bf16x8 bfr[4][2];
        bf16x8 af0[2], af1[2], af2[2], af3[2];
        // ---- phase A: ds B(all)+quads 0,1 (slabs 0,2); stage A1,A3(kt+1)->nb
        LDB(); LDAQ(af0, 0); LDAQ(af1, 1);
        if (kt < 7) { STAGE_A(nb, 1, kt + 1); STAGE_A(nb, 3, kt + 1); }
        BARRIER();
        MFMA_PAIR(0, af0, 1, af1);
        BARRIER();
        // ---- phase B: ds quads 2,3 (slabs 1,3); stage B0-3,A0,A2(kt+2)->cb
        //      (stage targets: B + A slabs 0,2 — disjoint from phase-B reads)
        LDAQ(af2, 2); LDAQ(af3, 3);
        if (kt < 6) {
            STAGE_B(cb, 0, kt + 2); STAGE_B(cb, 1, kt + 2);
            STAGE_B(cb, 2, kt + 2); STAGE_B(cb, 3, kt + 2);
            STAGE_A(cb, 0, kt + 2); STAGE_A(cb, 2, kt + 2);
        }
        BARRIER();
        MFMA_PAIR(2, af2, 3, af3);
        if (kt < 6) asm volatile("s_waitcnt vmcnt(6)" ::: "memory");
        else        asm volatile("s_waitcnt vmcnt(0)" ::: "memory");
        BARRIER();
    }

    // ---- Epilogue: acc -> LDS [128][132] fp32 -> line-aligned nt stores.
    float* lf = reinterpret_cast<float*>(lds);
    #pragma unroll
    for (int mi = 0; mi < 4; ++mi) {
        const int lrow = wr + mi * 16 + fr;
        const int lab = labels[m0 + lrow];
        #pragma unroll
        for (int ni = 0; ni < 4; ++ni) {
            const int col0 = wc + ni * 16 + kg * 4;
            const int gcol0 = n0 + col0;
            f32x4 v = acc[mi][ni];
            #pragma unroll
            for (int r = 0; r < 4; ++r) {
                if (gcol0 + r == lab) {
                    float c = v[r];
                    float sine = sqrtf(fmaxf(1.0f - c * c, 0.0f));
                    float phi = c * COS_M - sine * SIN_M;
                    v[r] = (c > THR) ? phi : (c - MM);
                }
            }
            v *= SCALE;
            *reinterpret_cast<f32x4*>(&lf[lrow * 132 + col0]) = v;
        }
    }
    __syncthreads();
    // read back: instruction covers 2 rows x 512B; nt store = fully aligned
    // 128B-line bursts. Tail strip: vectors are all-in/all-out (both %4==0).
    const int cc = lane & 31, rh = lane >> 5;
    #pragma unroll
    for (int s = 0; s < 16; ++s) {
        const int lrow = (w * 16 + s) * 2 + rh;
        f32x4 v = *reinterpret_cast<const f32x4*>(&lf[lrow * 132 + cc * 4]);
        const int gcol0 = n0 + cc * 4;
        if (gcol0 < Cq)
            __builtin_nontemporal_store(
                v, reinterpret_cast<f32x4*>(out + (size_t)(m0 + lrow) * Cq + gcol0));
    }
#undef STAGE_A
#undef STAGE_B
#undef BARRIER
#undef LDAQ
#undef LDB
#undef MFMA_PAIR
}

extern "C" void kernel_launch(void* const* d_in, const int* in_sizes, int n_in,
                              void* d_out, int out_size, void* d_ws, size_t ws_size,
                              hipStream_t stream)
{
    const float* emb    = (const float*)d_in[0];
    const int*   labels = (const int*)d_in[1];
    const float* weight = (const float*)d_in[2];
    float* out = (float*)d_out;

    unsigned short* Abf = (unsigned short*)d_ws;             // 2 MB
    unsigned short* Bbf = Abf + (size_t)Bq * Dq;             // 102.5 MB

    normalize_rows_kernel<<<Bq / 4, 256, 0, stream>>>(emb, Abf, Bq);
    normalize_rows_kernel<<<NPAD / 4, 256, 0, stream>>>(weight, Bbf, Cq);
    arc_gemm_kernel<<<16 * (NPAD / 128), 256, 67584, stream>>>(Abf, Bbf, labels, out);
}